// Round 1
// baseline (986.926 us; speedup 1.0000x reference)
//
#include <hip/hip_runtime.h>

#define D 64
#define N_USERS 100000
#define N_ITEMS 50000

// One wave (64 lanes) per edge; lane i handles feature dim i.
// Gather feat[src[e]] (coalesced 256B), scale by norm[e], atomicAdd into out[dst[e]].
__global__ void scatter_rel_kernel(const float* __restrict__ feat,
                                   const float* __restrict__ norm,
                                   const int* __restrict__ src,
                                   const int* __restrict__ dst,
                                   float* __restrict__ out,
                                   int n_edges) {
    const int lane = threadIdx.x & 63;
    const int wave_in_block = threadIdx.x >> 6;
    const int waves_per_block = blockDim.x >> 6;
    long long e = (long long)blockIdx.x * waves_per_block + wave_in_block;
    const long long stride = (long long)gridDim.x * waves_per_block;
    for (; e < n_edges; e += stride) {
        const int s = src[e];
        const int t = dst[e];
        const float nv = norm[e];
        const float v = nv * feat[(long long)s * D + lane];
        atomicAdd(&out[(long long)t * D + lane], v);
    }
}

extern "C" void kernel_launch(void* const* d_in, const int* in_sizes, int n_in,
                              void* d_out, int out_size, void* d_ws, size_t ws_size,
                              hipStream_t stream) {
    const float* user_feat = (const float*)d_in[0];   // [N_USERS, D]
    const float* item_feat = (const float*)d_in[1];   // [N_ITEMS, D]
    const float* norm_ui   = (const float*)d_in[2];   // [E, 1]
    const float* norm_iu   = (const float*)d_in[3];   // [E, 1]
    const int*   ui_src    = (const int*)d_in[4];     // user idx
    const int*   ui_dst    = (const int*)d_in[5];     // item idx
    const int*   iu_src    = (const int*)d_in[6];     // item idx
    const int*   iu_dst    = (const int*)d_in[7];     // user idx

    const int n_edges = in_sizes[4];

    float* h_user = (float*)d_out;                    // [N_USERS, D] first in return order
    float* h_item = (float*)d_out + (long long)N_USERS * D;  // [N_ITEMS, D]

    // d_out is poisoned to 0xAA before every timed call — zero it ourselves.
    hipMemsetAsync(d_out, 0, (size_t)out_size * sizeof(float), stream);

    // One wave per edge, 4 waves per 256-thread block.
    const int block = 256;
    const int waves_per_block = block / 64;
    const int grid = (n_edges + waves_per_block - 1) / waves_per_block;

    // relation (user -ui-> item): gather user feats, scatter-sum to items
    scatter_rel_kernel<<<grid, block, 0, stream>>>(user_feat, norm_ui, ui_src, ui_dst,
                                                   h_item, n_edges);
    // relation (item -iu-> user): gather item feats, scatter-sum to users
    scatter_rel_kernel<<<grid, block, 0, stream>>>(item_feat, norm_iu, iu_src, iu_dst,
                                                   h_user, n_edges);
}

// Round 2
// 831.975 us; speedup vs baseline: 1.1862x; 1.1862x over previous
//
#include <hip/hip_runtime.h>

#define D 64
#define N_USERS 100000
#define N_ITEMS 50000
#define SCAN_TILE 1024   // elements per scan tile (256 threads x 4)

static inline size_t align16(size_t x) { return (x + 15) & ~(size_t)15; }

// ---------------- CSR build ----------------

__global__ void hist_kernel(const int* __restrict__ dst, int* __restrict__ counts, int n) {
    int i = blockIdx.x * blockDim.x + threadIdx.x;
    int stride = gridDim.x * blockDim.x;
    for (; i < n; i += stride) atomicAdd(&counts[dst[i]], 1);
}

// Exclusive scan pass A: per-tile scan in place, tile totals out.
__global__ void scanA_kernel(int* __restrict__ data, int* __restrict__ tile_sums, int n) {
    __shared__ int lds[256];
    const int t = threadIdx.x;
    const int base = blockIdx.x * SCAN_TILE + t * 4;
    int v[4];
#pragma unroll
    for (int k = 0; k < 4; k++) v[k] = (base + k < n) ? data[base + k] : 0;
    const int s = v[0] + v[1] + v[2] + v[3];
    lds[t] = s;
    __syncthreads();
    for (int off = 1; off < 256; off <<= 1) {
        int x = (t >= off) ? lds[t - off] : 0;
        __syncthreads();
        lds[t] += x;
        __syncthreads();
    }
    const int incl = lds[t];
    const int excl = incl - s;
    if (t == 255) tile_sums[blockIdx.x] = incl;
    int run = excl;
#pragma unroll
    for (int k = 0; k < 4; k++) {
        int val = v[k];
        if (base + k < n) data[base + k] = run;
        run += val;
    }
}

// Pass B: single block exclusive-scans the tile sums (ntiles <= 128).
__global__ void scanB_kernel(int* __restrict__ tile_sums, int ntiles) {
    __shared__ int lds[128];
    const int t = threadIdx.x;
    int v = (t < ntiles) ? tile_sums[t] : 0;
    lds[t] = v;
    __syncthreads();
    for (int off = 1; off < 128; off <<= 1) {
        int x = (t >= off) ? lds[t - off] : 0;
        __syncthreads();
        lds[t] += x;
        __syncthreads();
    }
    if (t < ntiles) tile_sums[t] = lds[t] - v;  // exclusive
}

// Pass C: add tile offset; also emit fill cursor (copy of row starts).
__global__ void scanC_kernel(int* __restrict__ data, const int* __restrict__ tile_sums,
                             int* __restrict__ cursor, int n, int ncursor) {
    const int base = blockIdx.x * SCAN_TILE + threadIdx.x * 4;
    const int add = tile_sums[blockIdx.x];
#pragma unroll
    for (int k = 0; k < 4; k++) {
        int idx = base + k;
        if (idx < n) {
            int val = data[idx] + add;
            data[idx] = val;
            if (idx < ncursor) cursor[idx] = val;
        }
    }
}

// Scatter (src, norm) into dst-sorted slots.
__global__ void fill_kernel(const int* __restrict__ src, const int* __restrict__ dst,
                            const float* __restrict__ norm, int* __restrict__ cursor,
                            int2* __restrict__ sorted, int n) {
    int i = blockIdx.x * blockDim.x + threadIdx.x;
    int stride = gridDim.x * blockDim.x;
    for (; i < n; i += stride) {
        int d = dst[i];
        int slot = atomicAdd(&cursor[d], 1);
        sorted[slot] = make_int2(src[i], __float_as_int(norm[i]));
    }
}

// ---------------- Main pull kernel ----------------
// One wave per output row; lane = feature dim. No atomics.
__global__ void gather_rows_kernel(const float* __restrict__ feat,
                                   const int2* __restrict__ sorted,
                                   const int* __restrict__ offsets,
                                   float* __restrict__ out, int nrows) {
    const int lane = threadIdx.x & 63;
    const int wave = threadIdx.x >> 6;
    const int row = blockIdx.x * (blockDim.x >> 6) + wave;
    if (row >= nrows) return;
    const int start = offsets[row];
    const int end = offsets[row + 1];
    float acc = 0.f;
    int j = start;
    for (; j + 1 < end; j += 2) {
        int2 p0 = sorted[j];
        int2 p1 = sorted[j + 1];
        float f0 = feat[(long long)p0.x * D + lane];
        float f1 = feat[(long long)p1.x * D + lane];
        acc += __int_as_float(p0.y) * f0;
        acc += __int_as_float(p1.y) * f1;
    }
    if (j < end) {
        int2 p = sorted[j];
        acc += __int_as_float(p.y) * feat[(long long)p.x * D + lane];
    }
    out[(long long)row * D + lane] = acc;
}

// ---------------- Fallback (round-1 proven path) ----------------
__global__ void scatter_rel_kernel(const float* __restrict__ feat,
                                   const float* __restrict__ norm,
                                   const int* __restrict__ src,
                                   const int* __restrict__ dst,
                                   float* __restrict__ out, int n_edges) {
    const int lane = threadIdx.x & 63;
    const int wave_in_block = threadIdx.x >> 6;
    const int waves_per_block = blockDim.x >> 6;
    long long e = (long long)blockIdx.x * waves_per_block + wave_in_block;
    const long long stride = (long long)gridDim.x * waves_per_block;
    for (; e < n_edges; e += stride) {
        const int s = src[e];
        const int t = dst[e];
        const float nv = norm[e];
        atomicAdd(&out[(long long)t * D + lane], nv * feat[(long long)s * D + lane]);
    }
}

extern "C" void kernel_launch(void* const* d_in, const int* in_sizes, int n_in,
                              void* d_out, int out_size, void* d_ws, size_t ws_size,
                              hipStream_t stream) {
    const float* user_feat = (const float*)d_in[0];
    const float* item_feat = (const float*)d_in[1];
    const float* norm_ui   = (const float*)d_in[2];
    const float* norm_iu   = (const float*)d_in[3];
    const int*   ui_src    = (const int*)d_in[4];  // user idx
    const int*   ui_dst    = (const int*)d_in[5];  // item idx
    const int*   iu_src    = (const int*)d_in[6];  // item idx
    const int*   iu_dst    = (const int*)d_in[7];  // user idx

    const int n_ui = in_sizes[4];
    const int n_iu = in_sizes[6];

    float* h_user = (float*)d_out;                              // [N_USERS, D]
    float* h_item = (float*)d_out + (long long)N_USERS * D;     // [N_ITEMS, D]

    // ---- workspace layout ----
    char* ws = (char*)d_ws;
    size_t off = 0;
    // counts/offsets arrays contiguous so one memset zeros both
    int* ui_off = (int*)(ws + off); off += (size_t)(N_ITEMS + 1) * 4;
    int* iu_off = (int*)(ws + off); off += (size_t)(N_USERS + 1) * 4;
    size_t zero_bytes = off;  // zero [0, off)
    off = align16(off);
    int* ui_cursor = (int*)(ws + off); off += align16((size_t)N_ITEMS * 4);
    int* iu_cursor = (int*)(ws + off); off += align16((size_t)N_USERS * 4);
    int* ui_tiles  = (int*)(ws + off); off += align16(128 * 4);
    int* iu_tiles  = (int*)(ws + off); off += align16(128 * 4);
    int2* sorted_ui = (int2*)(ws + off); off += align16((size_t)n_ui * 8);
    int2* sorted_iu = (int2*)(ws + off); off += align16((size_t)n_iu * 8);
    const size_t needed = off;

    if (ws_size < needed) {
        // Fallback: proven atomic-scatter path.
        hipMemsetAsync(d_out, 0, (size_t)out_size * sizeof(float), stream);
        const int block = 256, wpb = block / 64;
        scatter_rel_kernel<<<(n_ui + wpb - 1) / wpb, block, 0, stream>>>(
            user_feat, norm_ui, ui_src, ui_dst, h_item, n_ui);
        scatter_rel_kernel<<<(n_iu + wpb - 1) / wpb, block, 0, stream>>>(
            item_feat, norm_iu, iu_src, iu_dst, h_user, n_iu);
        return;
    }

    hipMemsetAsync(d_ws, 0, zero_bytes, stream);

    const int block = 256;
    const int hist_grid_ui = (n_ui + block - 1) / block;
    const int hist_grid_iu = (n_iu + block - 1) / block;

    // 1. histograms of dst
    hist_kernel<<<hist_grid_ui, block, 0, stream>>>(ui_dst, ui_off, n_ui);
    hist_kernel<<<hist_grid_iu, block, 0, stream>>>(iu_dst, iu_off, n_iu);

    // 2. exclusive scan (N+1 elements so offsets[N] = total)
    const int n_ui_off = N_ITEMS + 1, n_iu_off = N_USERS + 1;
    const int tiles_ui = (n_ui_off + SCAN_TILE - 1) / SCAN_TILE;   // 50
    const int tiles_iu = (n_iu_off + SCAN_TILE - 1) / SCAN_TILE;   // 98
    scanA_kernel<<<tiles_ui, 256, 0, stream>>>(ui_off, ui_tiles, n_ui_off);
    scanA_kernel<<<tiles_iu, 256, 0, stream>>>(iu_off, iu_tiles, n_iu_off);
    scanB_kernel<<<1, 128, 0, stream>>>(ui_tiles, tiles_ui);
    scanB_kernel<<<1, 128, 0, stream>>>(iu_tiles, tiles_iu);
    scanC_kernel<<<tiles_ui, 256, 0, stream>>>(ui_off, ui_tiles, ui_cursor, n_ui_off, N_ITEMS);
    scanC_kernel<<<tiles_iu, 256, 0, stream>>>(iu_off, iu_tiles, iu_cursor, n_iu_off, N_USERS);

    // 3. scatter-fill (src, norm) into dst-sorted order
    fill_kernel<<<hist_grid_ui, block, 0, stream>>>(ui_src, ui_dst, norm_ui, ui_cursor,
                                                    sorted_ui, n_ui);
    fill_kernel<<<hist_grid_iu, block, 0, stream>>>(iu_src, iu_dst, norm_iu, iu_cursor,
                                                    sorted_iu, n_iu);

    // 4. pull-gather per output row (no atomics, full overwrite of d_out)
    const int wpb = block / 64;
    gather_rows_kernel<<<(N_ITEMS + wpb - 1) / wpb, block, 0, stream>>>(
        user_feat, sorted_ui, ui_off, h_item, N_ITEMS);
    gather_rows_kernel<<<(N_USERS + wpb - 1) / wpb, block, 0, stream>>>(
        item_feat, sorted_iu, iu_off, h_user, N_USERS);
}

// Round 3
// 697.381 us; speedup vs baseline: 1.4152x; 1.1930x over previous
//
#include <hip/hip_runtime.h>

#define D 64
#define N_USERS 100000
#define N_ITEMS 50000

static inline size_t align16(size_t x) { return (x + 15) & ~(size_t)15; }

// ---------------- linked-list build ----------------
// Reverse adjacency list: head[dst] -> last edge, next[e] -> previous edge w/ same dst.
// next[] store is coalesced (sequential in e); atomics hit a small cache-resident head[].
__global__ void build_list_kernel(const int* __restrict__ dst,
                                  int* __restrict__ head,
                                  int* __restrict__ next, int n) {
    int i = blockIdx.x * blockDim.x + threadIdx.x;
    int stride = gridDim.x * blockDim.x;
    for (; i < n; i += stride) {
        next[i] = atomicExch(&head[dst[i]], i);
    }
}

// ---------------- pull gather ----------------
// One wave (64 lanes) per output row; lane = feature dim. Walk the row's chain.
// src/norm/next loads are independent per step; only next[e] is on the serial path.
__global__ void gather_list_kernel(const float* __restrict__ feat,
                                   const float* __restrict__ norm,
                                   const int* __restrict__ src,
                                   const int* __restrict__ head,
                                   const int* __restrict__ next,
                                   float* __restrict__ out, int nrows) {
    const int lane = threadIdx.x & 63;
    const int wave = threadIdx.x >> 6;
    const int row = blockIdx.x * (blockDim.x >> 6) + wave;
    if (row >= nrows) return;

    int e = head[row];
    float acc = 0.f;
    while (e >= 0) {
        const int s = src[e];
        const float nv = norm[e];
        const int en = next[e];
        acc = fmaf(nv, feat[(long long)s * D + lane], acc);
        e = en;
    }
    out[(long long)row * D + lane] = acc;
}

// ---------------- fallback (round-1 proven path) ----------------
__global__ void scatter_rel_kernel(const float* __restrict__ feat,
                                   const float* __restrict__ norm,
                                   const int* __restrict__ src,
                                   const int* __restrict__ dst,
                                   float* __restrict__ out, int n_edges) {
    const int lane = threadIdx.x & 63;
    const int wave_in_block = threadIdx.x >> 6;
    const int waves_per_block = blockDim.x >> 6;
    long long e = (long long)blockIdx.x * waves_per_block + wave_in_block;
    const long long stride = (long long)gridDim.x * waves_per_block;
    for (; e < n_edges; e += stride) {
        const int s = src[e];
        const int t = dst[e];
        const float nv = norm[e];
        atomicAdd(&out[(long long)t * D + lane], nv * feat[(long long)s * D + lane]);
    }
}

extern "C" void kernel_launch(void* const* d_in, const int* in_sizes, int n_in,
                              void* d_out, int out_size, void* d_ws, size_t ws_size,
                              hipStream_t stream) {
    const float* user_feat = (const float*)d_in[0];
    const float* item_feat = (const float*)d_in[1];
    const float* norm_ui   = (const float*)d_in[2];
    const float* norm_iu   = (const float*)d_in[3];
    const int*   ui_src    = (const int*)d_in[4];  // user idx
    const int*   ui_dst    = (const int*)d_in[5];  // item idx
    const int*   iu_src    = (const int*)d_in[6];  // item idx
    const int*   iu_dst    = (const int*)d_in[7];  // user idx

    const int n_ui = in_sizes[4];
    const int n_iu = in_sizes[6];

    float* h_user = (float*)d_out;                              // [N_USERS, D]
    float* h_item = (float*)d_out + (long long)N_USERS * D;     // [N_ITEMS, D]

    // ---- workspace layout ----
    char* ws = (char*)d_ws;
    size_t off = 0;
    // head arrays contiguous so one 0xFF memset initializes both to -1
    int* head_ui = (int*)(ws + off); off += (size_t)N_ITEMS * 4;   // per item
    int* head_iu = (int*)(ws + off); off += (size_t)N_USERS * 4;   // per user
    const size_t head_bytes = off;
    off = align16(off);
    int* next_ui = (int*)(ws + off); off += align16((size_t)n_ui * 4);
    int* next_iu = (int*)(ws + off); off += align16((size_t)n_iu * 4);
    const size_t needed = off;

    if (ws_size < needed) {
        // Fallback: proven atomic-scatter path.
        hipMemsetAsync(d_out, 0, (size_t)out_size * sizeof(float), stream);
        const int block = 256, wpb = block / 64;
        scatter_rel_kernel<<<(n_ui + wpb - 1) / wpb, block, 0, stream>>>(
            user_feat, norm_ui, ui_src, ui_dst, h_item, n_ui);
        scatter_rel_kernel<<<(n_iu + wpb - 1) / wpb, block, 0, stream>>>(
            item_feat, norm_iu, iu_src, iu_dst, h_user, n_iu);
        return;
    }

    // head = -1 everywhere (0xFF bytes). next[] is fully overwritten by build.
    hipMemsetAsync(d_ws, 0xFF, head_bytes, stream);

    const int block = 256;
    build_list_kernel<<<(n_ui + block - 1) / block, block, 0, stream>>>(
        ui_dst, head_ui, next_ui, n_ui);
    build_list_kernel<<<(n_iu + block - 1) / block, block, 0, stream>>>(
        iu_dst, head_iu, next_iu, n_iu);

    // Pull-gather per output row (no atomics; every row fully overwritten).
    const int wpb = block / 64;
    gather_list_kernel<<<(N_ITEMS + wpb - 1) / wpb, block, 0, stream>>>(
        user_feat, norm_ui, ui_src, head_ui, next_ui, h_item, N_ITEMS);
    gather_list_kernel<<<(N_USERS + wpb - 1) / wpb, block, 0, stream>>>(
        item_feat, norm_iu, iu_src, head_iu, next_iu, h_user, N_USERS);
}

// Round 4
// 577.447 us; speedup vs baseline: 1.7091x; 1.2077x over previous
//
#include <hip/hip_runtime.h>

#define D 64
#define N_USERS 100000
#define N_ITEMS 50000

static inline size_t align16(size_t x) { return (x + 15) & ~(size_t)15; }

// ---------------- linked-list build (both relations, one launch) ----------------
// Reverse adjacency: head[dst] -> last edge, next[e] -> previous edge w/ same dst.
// next[] store is coalesced; atomics hit small cache-resident head arrays.
__global__ void build_both_kernel(const int* __restrict__ ui_dst,
                                  const int* __restrict__ iu_dst,
                                  int* __restrict__ head_ui,  // per item
                                  int* __restrict__ head_iu,  // per user
                                  int* __restrict__ next_ui,
                                  int* __restrict__ next_iu,
                                  int n_ui, int n_iu) {
    int i = blockIdx.x * blockDim.x + threadIdx.x;
    const int total = n_ui + n_iu;
    const int stride = gridDim.x * blockDim.x;
    for (; i < total; i += stride) {
        if (i < n_ui) {
            next_ui[i] = atomicExch(&head_ui[ui_dst[i]], i);
        } else {
            const int j = i - n_ui;
            next_iu[j] = atomicExch(&head_iu[iu_dst[j]], j);
        }
    }
}

// ---------------- pull gather, 4 chains per wave ----------------
// Quarter-wave (16 lanes) per output row; lane handles float4 of the D=64 row.
// 4 independent chain walks per wave -> 4x memory-level parallelism vs 1 chain/wave.
// Rows [0, N_ITEMS) pull from user_feat via ui lists; rows [N_ITEMS, N_ITEMS+N_USERS)
// pull from item_feat via iu lists.
__global__ void gather_both_kernel(const float* __restrict__ user_feat,
                                   const float* __restrict__ item_feat,
                                   const float* __restrict__ norm_ui,
                                   const float* __restrict__ norm_iu,
                                   const int* __restrict__ src_ui,
                                   const int* __restrict__ src_iu,
                                   const int* __restrict__ head_ui,
                                   const int* __restrict__ head_iu,
                                   const int* __restrict__ next_ui,
                                   const int* __restrict__ next_iu,
                                   float* __restrict__ h_user,
                                   float* __restrict__ h_item) {
    const int t = blockIdx.x * blockDim.x + threadIdx.x;
    const int sub = t & 15;        // lane within quarter-wave
    const int row = t >> 4;        // global output row
    const int NR = N_ITEMS + N_USERS;
    if (row >= NR) return;

    const bool item_side = row < N_ITEMS;
    const float* __restrict__ feat = item_side ? user_feat : item_feat;
    const float* __restrict__ norm = item_side ? norm_ui : norm_iu;
    const int*   __restrict__ src  = item_side ? src_ui  : src_iu;
    const int*   __restrict__ next = item_side ? next_ui : next_iu;
    const int r = item_side ? row : row - N_ITEMS;

    int e = item_side ? head_ui[r] : head_iu[r];
    float4 acc = make_float4(0.f, 0.f, 0.f, 0.f);
    while (e >= 0) {
        const int s = src[e];
        const float nv = norm[e];
        const int en = next[e];
        const float4 f = *(const float4*)(feat + (long long)s * D + sub * 4);
        acc.x = fmaf(nv, f.x, acc.x);
        acc.y = fmaf(nv, f.y, acc.y);
        acc.z = fmaf(nv, f.z, acc.z);
        acc.w = fmaf(nv, f.w, acc.w);
        e = en;
    }
    float* __restrict__ out = item_side ? (h_item + (long long)r * D)
                                        : (h_user + (long long)r * D);
    *(float4*)(out + sub * 4) = acc;
}

// ---------------- fallback (round-1 proven path) ----------------
__global__ void scatter_rel_kernel(const float* __restrict__ feat,
                                   const float* __restrict__ norm,
                                   const int* __restrict__ src,
                                   const int* __restrict__ dst,
                                   float* __restrict__ out, int n_edges) {
    const int lane = threadIdx.x & 63;
    const int wave_in_block = threadIdx.x >> 6;
    const int waves_per_block = blockDim.x >> 6;
    long long e = (long long)blockIdx.x * waves_per_block + wave_in_block;
    const long long stride = (long long)gridDim.x * waves_per_block;
    for (; e < n_edges; e += stride) {
        const int s = src[e];
        const int t = dst[e];
        const float nv = norm[e];
        atomicAdd(&out[(long long)t * D + lane], nv * feat[(long long)s * D + lane]);
    }
}

extern "C" void kernel_launch(void* const* d_in, const int* in_sizes, int n_in,
                              void* d_out, int out_size, void* d_ws, size_t ws_size,
                              hipStream_t stream) {
    const float* user_feat = (const float*)d_in[0];
    const float* item_feat = (const float*)d_in[1];
    const float* norm_ui   = (const float*)d_in[2];
    const float* norm_iu   = (const float*)d_in[3];
    const int*   ui_src    = (const int*)d_in[4];  // user idx
    const int*   ui_dst    = (const int*)d_in[5];  // item idx
    const int*   iu_src    = (const int*)d_in[6];  // item idx
    const int*   iu_dst    = (const int*)d_in[7];  // user idx

    const int n_ui = in_sizes[4];
    const int n_iu = in_sizes[6];

    float* h_user = (float*)d_out;                              // [N_USERS, D]
    float* h_item = (float*)d_out + (long long)N_USERS * D;     // [N_ITEMS, D]

    // ---- workspace layout ----
    char* ws = (char*)d_ws;
    size_t off = 0;
    // head arrays contiguous so one 0xFF memset initializes both to -1
    int* head_ui = (int*)(ws + off); off += (size_t)N_ITEMS * 4;   // per item
    int* head_iu = (int*)(ws + off); off += (size_t)N_USERS * 4;   // per user
    const size_t head_bytes = off;
    off = align16(off);
    int* next_ui = (int*)(ws + off); off += align16((size_t)n_ui * 4);
    int* next_iu = (int*)(ws + off); off += align16((size_t)n_iu * 4);
    const size_t needed = off;

    if (ws_size < needed) {
        // Fallback: proven atomic-scatter path.
        hipMemsetAsync(d_out, 0, (size_t)out_size * sizeof(float), stream);
        const int block = 256, wpb = block / 64;
        scatter_rel_kernel<<<(n_ui + wpb - 1) / wpb, block, 0, stream>>>(
            user_feat, norm_ui, ui_src, ui_dst, h_item, n_ui);
        scatter_rel_kernel<<<(n_iu + wpb - 1) / wpb, block, 0, stream>>>(
            item_feat, norm_iu, iu_src, iu_dst, h_user, n_iu);
        return;
    }

    // head = -1 everywhere (0xFF bytes). next[] is fully overwritten by build.
    hipMemsetAsync(d_ws, 0xFF, head_bytes, stream);

    const int block = 256;
    const int total_edges = n_ui + n_iu;
    build_both_kernel<<<(total_edges + block - 1) / block, block, 0, stream>>>(
        ui_dst, iu_dst, head_ui, head_iu, next_ui, next_iu, n_ui, n_iu);

    // Pull-gather: quarter-wave per row, both relations in one grid.
    const long long total_threads = (long long)(N_ITEMS + N_USERS) * 16;
    const int grid = (int)((total_threads + block - 1) / block);
    gather_both_kernel<<<grid, block, 0, stream>>>(
        user_feat, item_feat, norm_ui, norm_iu, ui_src, iu_src,
        head_ui, head_iu, next_ui, next_iu, h_user, h_item);
}

// Round 5
// 492.511 us; speedup vs baseline: 2.0039x; 1.1725x over previous
//
#include <hip/hip_runtime.h>

#define D 64
#define N_USERS 100000
#define N_ITEMS 50000

static inline size_t align16(size_t x) { return (x + 15) & ~(size_t)15; }

// fp32 -> bf16 (RNE), packed two per uint (elem 2k low, 2k+1 high)
__device__ inline unsigned int bf16rne(float f) {
    unsigned int b = __float_as_uint(f);
    return (b + 0x7fffu + ((b >> 16) & 1u)) >> 16;
}
__device__ inline float bf16lo(unsigned int u) { return __uint_as_float(u << 16); }
__device__ inline float bf16hi(unsigned int u) { return __uint_as_float(u & 0xffff0000u); }

// ---------------- feature conversion fp32 -> bf16 ----------------
// Thread handles 4 consecutive floats -> 2 packed uints (8 B store).
__global__ void convert_feats_kernel(const float* __restrict__ user_feat,
                                     const float* __restrict__ item_feat,
                                     unsigned int* __restrict__ user16,  // packed bf16x2
                                     unsigned int* __restrict__ item16) {
    const long long USER_ELEMS = (long long)N_USERS * D;
    const long long TOTAL = USER_ELEMS + (long long)N_ITEMS * D;
    long long i4 = ((long long)blockIdx.x * blockDim.x + threadIdx.x) * 4;
    const long long stride = (long long)gridDim.x * blockDim.x * 4;
    for (; i4 < TOTAL; i4 += stride) {
        const float4 v = (i4 < USER_ELEMS)
            ? *(const float4*)(user_feat + i4)
            : *(const float4*)(item_feat + (i4 - USER_ELEMS));
        uint2 p;
        p.x = bf16rne(v.x) | (bf16rne(v.y) << 16);
        p.y = bf16rne(v.z) | (bf16rne(v.w) << 16);
        unsigned int* dst = (i4 < USER_ELEMS) ? (user16 + (i4 >> 1))
                                              : (item16 + ((i4 - USER_ELEMS) >> 1));
        *(uint2*)dst = p;
    }
}

// ---------------- linked-list build: packed 16B records ----------------
// rec[e] = {next, src, norm_bits, 0}; record store coalesced (sequential e);
// atomics hit small cache-resident head arrays.
__global__ void build_both_kernel(const int* __restrict__ ui_src,
                                  const int* __restrict__ iu_src,
                                  const int* __restrict__ ui_dst,
                                  const int* __restrict__ iu_dst,
                                  const float* __restrict__ norm_ui,
                                  const float* __restrict__ norm_iu,
                                  int* __restrict__ head_ui,   // per item
                                  int* __restrict__ head_iu,   // per user
                                  int4* __restrict__ rec_ui,
                                  int4* __restrict__ rec_iu,
                                  int n_ui, int n_iu) {
    int i = blockIdx.x * blockDim.x + threadIdx.x;
    const int total = n_ui + n_iu;
    const int stride = gridDim.x * blockDim.x;
    for (; i < total; i += stride) {
        if (i < n_ui) {
            const int nx = atomicExch(&head_ui[ui_dst[i]], i);
            rec_ui[i] = make_int4(nx, ui_src[i], __float_as_int(norm_ui[i]), 0);
        } else {
            const int j = i - n_ui;
            const int nx = atomicExch(&head_iu[iu_dst[j]], j);
            rec_iu[j] = make_int4(nx, iu_src[j], __float_as_int(norm_iu[j]), 0);
        }
    }
}

// ---------------- pull gather: bf16 feats, 8 chains/wave ----------------
// 8 lanes per output row (lane loads uint4 = 8 bf16 = 16B of the 128B row).
// One 16B record load per chain step carries next+src+norm together.
__global__ void gather_bf16_kernel(const unsigned int* __restrict__ user16,
                                   const unsigned int* __restrict__ item16,
                                   const int4* __restrict__ rec_ui,
                                   const int4* __restrict__ rec_iu,
                                   const int* __restrict__ head_ui,
                                   const int* __restrict__ head_iu,
                                   float* __restrict__ h_user,
                                   float* __restrict__ h_item) {
    const long long t = (long long)blockIdx.x * blockDim.x + threadIdx.x;
    const int sub = (int)(t & 7);
    const long long row = t >> 3;
    const int NR = N_ITEMS + N_USERS;
    if (row >= NR) return;

    const bool item_side = row < N_ITEMS;
    const int r = item_side ? (int)row : (int)(row - N_ITEMS);
    const uint4* __restrict__ feat = (const uint4*)(item_side ? user16 : item16);
    const int4* __restrict__ rec = item_side ? rec_ui : rec_iu;
    int e = item_side ? head_ui[r] : head_iu[r];

    float a0 = 0.f, a1 = 0.f, a2 = 0.f, a3 = 0.f;
    float a4 = 0.f, a5 = 0.f, a6 = 0.f, a7 = 0.f;
    while (e >= 0) {
        const int4 R = rec[e];                          // {next, src, norm_bits, 0}
        const uint4 f = feat[(long long)R.y * 8 + sub]; // 8 bf16 of src row
        const float nv = __int_as_float(R.z);
        a0 = fmaf(nv, bf16lo(f.x), a0);
        a1 = fmaf(nv, bf16hi(f.x), a1);
        a2 = fmaf(nv, bf16lo(f.y), a2);
        a3 = fmaf(nv, bf16hi(f.y), a3);
        a4 = fmaf(nv, bf16lo(f.z), a4);
        a5 = fmaf(nv, bf16hi(f.z), a5);
        a6 = fmaf(nv, bf16lo(f.w), a6);
        a7 = fmaf(nv, bf16hi(f.w), a7);
        e = R.x;
    }
    float* __restrict__ out = (item_side ? (h_item + (long long)r * D)
                                         : (h_user + (long long)r * D)) + sub * 8;
    *(float4*)out = make_float4(a0, a1, a2, a3);
    *(float4*)(out + 4) = make_float4(a4, a5, a6, a7);
}

// ---------------- Tier B: round-4 proven path (fp32, next[] only) ----------------
__global__ void build_next_kernel(const int* __restrict__ ui_dst,
                                  const int* __restrict__ iu_dst,
                                  int* __restrict__ head_ui, int* __restrict__ head_iu,
                                  int* __restrict__ next_ui, int* __restrict__ next_iu,
                                  int n_ui, int n_iu) {
    int i = blockIdx.x * blockDim.x + threadIdx.x;
    const int total = n_ui + n_iu;
    const int stride = gridDim.x * blockDim.x;
    for (; i < total; i += stride) {
        if (i < n_ui) next_ui[i] = atomicExch(&head_ui[ui_dst[i]], i);
        else { const int j = i - n_ui; next_iu[j] = atomicExch(&head_iu[iu_dst[j]], j); }
    }
}

__global__ void gather_f32_kernel(const float* __restrict__ user_feat,
                                  const float* __restrict__ item_feat,
                                  const float* __restrict__ norm_ui,
                                  const float* __restrict__ norm_iu,
                                  const int* __restrict__ src_ui,
                                  const int* __restrict__ src_iu,
                                  const int* __restrict__ head_ui,
                                  const int* __restrict__ head_iu,
                                  const int* __restrict__ next_ui,
                                  const int* __restrict__ next_iu,
                                  float* __restrict__ h_user,
                                  float* __restrict__ h_item) {
    const int t = blockIdx.x * blockDim.x + threadIdx.x;
    const int sub = t & 15;
    const int row = t >> 4;
    const int NR = N_ITEMS + N_USERS;
    if (row >= NR) return;
    const bool item_side = row < N_ITEMS;
    const float* __restrict__ feat = item_side ? user_feat : item_feat;
    const float* __restrict__ norm = item_side ? norm_ui : norm_iu;
    const int* __restrict__ src = item_side ? src_ui : src_iu;
    const int* __restrict__ next = item_side ? next_ui : next_iu;
    const int r = item_side ? row : row - N_ITEMS;
    int e = item_side ? head_ui[r] : head_iu[r];
    float4 acc = make_float4(0.f, 0.f, 0.f, 0.f);
    while (e >= 0) {
        const int s = src[e];
        const float nv = norm[e];
        const int en = next[e];
        const float4 f = *(const float4*)(feat + (long long)s * D + sub * 4);
        acc.x = fmaf(nv, f.x, acc.x); acc.y = fmaf(nv, f.y, acc.y);
        acc.z = fmaf(nv, f.z, acc.z); acc.w = fmaf(nv, f.w, acc.w);
        e = en;
    }
    float* out = item_side ? (h_item + (long long)r * D) : (h_user + (long long)r * D);
    *(float4*)(out + sub * 4) = acc;
}

// ---------------- Tier C: atomic scatter ----------------
__global__ void scatter_rel_kernel(const float* __restrict__ feat,
                                   const float* __restrict__ norm,
                                   const int* __restrict__ src,
                                   const int* __restrict__ dst,
                                   float* __restrict__ out, int n_edges) {
    const int lane = threadIdx.x & 63;
    const int wib = threadIdx.x >> 6;
    const int wpb = blockDim.x >> 6;
    long long e = (long long)blockIdx.x * wpb + wib;
    const long long stride = (long long)gridDim.x * wpb;
    for (; e < n_edges; e += stride) {
        atomicAdd(&out[(long long)dst[e] * D + lane],
                  norm[e] * feat[(long long)src[e] * D + lane]);
    }
}

extern "C" void kernel_launch(void* const* d_in, const int* in_sizes, int n_in,
                              void* d_out, int out_size, void* d_ws, size_t ws_size,
                              hipStream_t stream) {
    const float* user_feat = (const float*)d_in[0];
    const float* item_feat = (const float*)d_in[1];
    const float* norm_ui   = (const float*)d_in[2];
    const float* norm_iu   = (const float*)d_in[3];
    const int*   ui_src    = (const int*)d_in[4];  // user idx
    const int*   ui_dst    = (const int*)d_in[5];  // item idx
    const int*   iu_src    = (const int*)d_in[6];  // item idx
    const int*   iu_dst    = (const int*)d_in[7];  // user idx

    const int n_ui = in_sizes[4];
    const int n_iu = in_sizes[6];

    float* h_user = (float*)d_out;                              // [N_USERS, D]
    float* h_item = (float*)d_out + (long long)N_USERS * D;     // [N_ITEMS, D]

    const int block = 256;

    // ---- Tier A workspace layout ----
    char* ws = (char*)d_ws;
    size_t off = 0;
    int* head_ui = (int*)(ws + off); off += (size_t)N_ITEMS * 4;
    int* head_iu = (int*)(ws + off); off += (size_t)N_USERS * 4;
    const size_t head_bytes = off;
    off = align16(off);
    int4* rec_ui = (int4*)(ws + off); off += align16((size_t)n_ui * 16);
    int4* rec_iu = (int4*)(ws + off); off += align16((size_t)n_iu * 16);
    unsigned int* user16 = (unsigned int*)(ws + off); off += align16((size_t)N_USERS * D * 2);
    unsigned int* item16 = (unsigned int*)(ws + off); off += align16((size_t)N_ITEMS * D * 2);
    const size_t neededA = off;

    if (ws_size >= neededA) {
        hipMemsetAsync(d_ws, 0xFF, head_bytes, stream);  // heads = -1

        const long long cv_threads = ((long long)(N_USERS + N_ITEMS) * D) / 4;
        convert_feats_kernel<<<(int)((cv_threads + block - 1) / block), block, 0, stream>>>(
            user_feat, item_feat, user16, item16);

        const int total_edges = n_ui + n_iu;
        build_both_kernel<<<(total_edges + block - 1) / block, block, 0, stream>>>(
            ui_src, iu_src, ui_dst, iu_dst, norm_ui, norm_iu,
            head_ui, head_iu, rec_ui, rec_iu, n_ui, n_iu);

        const long long g_threads = (long long)(N_ITEMS + N_USERS) * 8;
        gather_bf16_kernel<<<(int)((g_threads + block - 1) / block), block, 0, stream>>>(
            user16, item16, rec_ui, rec_iu, head_ui, head_iu, h_user, h_item);
        return;
    }

    // ---- Tier B: round-4 structure (next arrays only) ----
    off = head_bytes;
    off = align16(off);
    int* next_ui = (int*)(ws + off); off += align16((size_t)n_ui * 4);
    int* next_iu = (int*)(ws + off); off += align16((size_t)n_iu * 4);
    const size_t neededB = off;

    if (ws_size >= neededB) {
        hipMemsetAsync(d_ws, 0xFF, head_bytes, stream);
        const int total_edges = n_ui + n_iu;
        build_next_kernel<<<(total_edges + block - 1) / block, block, 0, stream>>>(
            ui_dst, iu_dst, head_ui, head_iu, next_ui, next_iu, n_ui, n_iu);
        const long long g_threads = (long long)(N_ITEMS + N_USERS) * 16;
        gather_f32_kernel<<<(int)((g_threads + block - 1) / block), block, 0, stream>>>(
            user_feat, item_feat, norm_ui, norm_iu, ui_src, iu_src,
            head_ui, head_iu, next_ui, next_iu, h_user, h_item);
        return;
    }

    // ---- Tier C: atomic scatter ----
    hipMemsetAsync(d_out, 0, (size_t)out_size * sizeof(float), stream);
    const int wpb = block / 64;
    scatter_rel_kernel<<<(n_ui + wpb - 1) / wpb, block, 0, stream>>>(
        user_feat, norm_ui, ui_src, ui_dst, h_item, n_ui);
    scatter_rel_kernel<<<(n_iu + wpb - 1) / wpb, block, 0, stream>>>(
        item_feat, norm_iu, iu_src, iu_dst, h_user, n_iu);
}

// Round 6
// 394.048 us; speedup vs baseline: 2.5046x; 1.2499x over previous
//
#include <hip/hip_runtime.h>

#define D 64
#define N_USERS 100000
#define N_ITEMS 50000
#define RW 64                              // rows per bucket
#define B_UI ((N_ITEMS + RW - 1) / RW)     // 782 item buckets
#define B_IU ((N_USERS + RW - 1) / RW)     // 1563 user buckets
#define B_TOT (B_UI + B_IU)                // 2345
#define CHUNK 8192                         // edges per pass-1 block
#define TILE 2048                          // pass-2 edge tile (8 per thread)
#define SCAN_TILE 1024

static inline size_t align16(size_t x) { return (x + 15) & ~(size_t)15; }

// fp32 -> bf16 (RNE), packed two per uint (elem 2k low, 2k+1 high)
__device__ inline unsigned int bf16rne(float f) {
    unsigned int b = __float_as_uint(f);
    return (b + 0x7fffu + ((b >> 16) & 1u)) >> 16;
}
__device__ inline float bf16lo(unsigned int u) { return __uint_as_float(u << 16); }
__device__ inline float bf16hi(unsigned int u) { return __uint_as_float(u & 0xffff0000u); }

// ---------------- feature conversion fp32 -> bf16 (proven round 5) ----------------
__global__ void convert_feats_kernel(const float* __restrict__ user_feat,
                                     const float* __restrict__ item_feat,
                                     unsigned int* __restrict__ user16,
                                     unsigned int* __restrict__ item16) {
    const long long USER_ELEMS = (long long)N_USERS * D;
    const long long TOTAL = USER_ELEMS + (long long)N_ITEMS * D;
    long long i4 = ((long long)blockIdx.x * blockDim.x + threadIdx.x) * 4;
    const long long stride = (long long)gridDim.x * blockDim.x * 4;
    for (; i4 < TOTAL; i4 += stride) {
        const float4 v = (i4 < USER_ELEMS)
            ? *(const float4*)(user_feat + i4)
            : *(const float4*)(item_feat + (i4 - USER_ELEMS));
        uint2 p;
        p.x = bf16rne(v.x) | (bf16rne(v.y) << 16);
        p.y = bf16rne(v.z) | (bf16rne(v.w) << 16);
        unsigned int* dst = (i4 < USER_ELEMS) ? (user16 + (i4 >> 1))
                                              : (item16 + ((i4 - USER_ELEMS) >> 1));
        *(uint2*)dst = p;
    }
}

// ---------------- pass 1a: per-chunk LDS histogram over dst buckets ----------------
__global__ void p1_count_kernel(const int* __restrict__ ui_dst,
                                const int* __restrict__ iu_dst,
                                int* __restrict__ counts,
                                int n_ui, int n_iu, int NB_ui, int NB) {
    __shared__ int hist[B_TOT];
    const int blk = blockIdx.x;
    for (int b = threadIdx.x; b < B_TOT; b += blockDim.x) hist[b] = 0;
    __syncthreads();
    const bool is_ui = blk < NB_ui;
    const int* dst = is_ui ? ui_dst : iu_dst;
    const int n = is_ui ? n_ui : n_iu;
    const int boff = is_ui ? 0 : B_UI;
    const int e0 = (is_ui ? blk : blk - NB_ui) * CHUNK;
    for (int k = 0; k < CHUNK; k += blockDim.x) {
        const int t = e0 + k + threadIdx.x;
        if (t < n) atomicAdd(&hist[boff + (dst[t] >> 6)], 1);
    }
    __syncthreads();
    for (int b = threadIdx.x; b < B_TOT; b += blockDim.x)
        counts[(long long)b * NB + blk] = hist[b];
}

// ---------------- scan machinery (round-2 proven scanA + wide single-block) -------
__global__ void scanA_kernel(int* __restrict__ data, int* __restrict__ tile_sums, int n) {
    __shared__ int lds[256];
    const int t = threadIdx.x;
    const int base = blockIdx.x * SCAN_TILE + t * 4;
    int v[4];
#pragma unroll
    for (int k = 0; k < 4; k++) v[k] = (base + k < n) ? data[base + k] : 0;
    const int s = v[0] + v[1] + v[2] + v[3];
    lds[t] = s;
    __syncthreads();
    for (int off = 1; off < 256; off <<= 1) {
        int x = (t >= off) ? lds[t - off] : 0;
        __syncthreads();
        lds[t] += x;
        __syncthreads();
    }
    const int incl = lds[t];
    const int excl = incl - s;
    if (t == 255) tile_sums[blockIdx.x] = incl;
    int run = excl;
#pragma unroll
    for (int k = 0; k < 4; k++) {
        int val = v[k];
        if (base + k < n) data[base + k] = run;
        run += val;
    }
}

// single block, 1024 threads, exclusive-scans up to 2048 tile sums
__global__ void scanB_big_kernel(int* __restrict__ tile_sums, int ntiles) {
    __shared__ int lds[1024];
    const int t = threadIdx.x;
    const int a = (2 * t < ntiles) ? tile_sums[2 * t] : 0;
    const int b = (2 * t + 1 < ntiles) ? tile_sums[2 * t + 1] : 0;
    const int s = a + b;
    lds[t] = s;
    __syncthreads();
    for (int off = 1; off < 1024; off <<= 1) {
        int x = (t >= off) ? lds[t - off] : 0;
        __syncthreads();
        lds[t] += x;
        __syncthreads();
    }
    const int excl = lds[t] - s;
    if (2 * t < ntiles) tile_sums[2 * t] = excl;
    if (2 * t + 1 < ntiles) tile_sums[2 * t + 1] = excl + a;
}

__global__ void scanC_kernel(int* __restrict__ data, const int* __restrict__ tile_sums, int n) {
    const int base = blockIdx.x * SCAN_TILE + threadIdx.x * 4;
    const int add = tile_sums[blockIdx.x];
#pragma unroll
    for (int k = 0; k < 4; k++) {
        const int i = base + k;
        if (i < n) data[i] += add;
    }
}

// ---------------- pass 1b: scatter edges bucket-grouped (LDS cursors) -------------
__global__ void p1_scatter_kernel(const int* __restrict__ ui_src,
                                  const int* __restrict__ iu_src,
                                  const int* __restrict__ ui_dst,
                                  const int* __restrict__ iu_dst,
                                  const float* __restrict__ norm_ui,
                                  const float* __restrict__ norm_iu,
                                  const int* __restrict__ counts,
                                  int2* __restrict__ part,
                                  int n_ui, int n_iu, int NB_ui, int NB) {
    __shared__ int cur[B_TOT];
    const int blk = blockIdx.x;
    for (int b = threadIdx.x; b < B_TOT; b += blockDim.x)
        cur[b] = counts[(long long)b * NB + blk];
    __syncthreads();
    const bool is_ui = blk < NB_ui;
    const int* src = is_ui ? ui_src : iu_src;
    const int* dst = is_ui ? ui_dst : iu_dst;
    const float* nrm = is_ui ? norm_ui : norm_iu;
    const int n = is_ui ? n_ui : n_iu;
    const int boff = is_ui ? 0 : B_UI;
    const int e0 = (is_ui ? blk : blk - NB_ui) * CHUNK;
    for (int k = 0; k < CHUNK; k += blockDim.x) {
        const int t = e0 + k + threadIdx.x;
        if (t < n) {
            const int d = dst[t];
            const int b = boff + (d >> 6);
            const int pos = atomicAdd(&cur[b], 1);
            part[pos] = make_int2(src[t] | ((d & 63) << 26), __float_as_int(nrm[t]));
        }
    }
}

// ---------------- pass 2: fused LDS counting-sort + gather --------------------
// Block = bucket (64 output rows). Tiles of 2048 edges: LDS sort by row, then
// waves accumulate rows with 8 independent bf16 feature loads in flight.
__global__ __launch_bounds__(256) void p2_gather_kernel(
        const uint4* __restrict__ user16, const uint4* __restrict__ item16,
        const int2* __restrict__ part, const int* __restrict__ counts,
        float* __restrict__ h_user, float* __restrict__ h_item,
        int NB, int n_total) {
    __shared__ int2 sorted[TILE];        // 16 KB
    __shared__ float acc[RW * D];        // 16 KB
    __shared__ int cnt[RW], offs[RW], cursor[RW], cnt2[RW];
    const int b = blockIdx.x;
    const int tid = threadIdx.x;
    const int lane = tid & 63;
    const int wave = tid >> 6;

    const int E0 = counts[(long long)b * NB];
    const int E1 = (b + 1 < B_TOT) ? counts[(long long)(b + 1) * NB] : n_total;

    const bool item_side = b < B_UI;
    const uint4* __restrict__ feat = item_side ? user16 : item16;
    const int baseRow = (item_side ? b : b - B_UI) * RW;

    for (int i = tid; i < RW * D; i += 256) acc[i] = 0.f;

    for (int base = E0; base < E1; base += TILE) {
        const int tileN = min(TILE, E1 - base);
        if (tid < RW) cnt[tid] = 0;
        __syncthreads();                           // A: acc/sorted free, cnt zeroed
        int2 v[TILE / 256];
#pragma unroll
        for (int k = 0; k < TILE / 256; k++) {
            const int t = tid + k * 256;
            if (t < tileN) {
                v[k] = part[base + t];
                atomicAdd(&cnt[((unsigned)v[k].x) >> 26], 1);
            }
        }
        __syncthreads();                           // B
        if (tid < RW) {  // wave 0 scans 64 counts
            const int c = cnt[tid];
            int incl = c;
            for (int dd = 1; dd < RW; dd <<= 1) {
                const int u = __shfl_up(incl, dd, 64);
                if (lane >= dd) incl += u;
            }
            offs[tid] = incl - c;
            cursor[tid] = incl - c;
            cnt2[tid] = c;
        }
        __syncthreads();                           // C
#pragma unroll
        for (int k = 0; k < TILE / 256; k++) {
            const int t = tid + k * 256;
            if (t < tileN) {
                const int r6 = ((unsigned)v[k].x) >> 26;
                const int pos = atomicAdd(&cursor[r6], 1);
                sorted[pos] = v[k];
            }
        }
        __syncthreads();                           // D
        for (int r = wave; r < RW; r += 4) {
            const int s = offs[r], c = cnt2[r];
            if (c == 0) continue;
            const int sub = lane & 7;
            float a0 = 0, a1 = 0, a2 = 0, a3 = 0, a4 = 0, a5 = 0, a6 = 0, a7 = 0;
            for (int j = lane >> 3; j < c; j += 8) {
                const int2 ed = sorted[s + j];
                const int srcRow = ed.x & 0x03FFFFFF;
                const float nv = __int_as_float(ed.y);
                const uint4 f = feat[srcRow * 8 + sub];
                a0 = fmaf(nv, bf16lo(f.x), a0);
                a1 = fmaf(nv, bf16hi(f.x), a1);
                a2 = fmaf(nv, bf16lo(f.y), a2);
                a3 = fmaf(nv, bf16hi(f.y), a3);
                a4 = fmaf(nv, bf16lo(f.z), a4);
                a5 = fmaf(nv, bf16hi(f.z), a5);
                a6 = fmaf(nv, bf16lo(f.w), a6);
                a7 = fmaf(nv, bf16hi(f.w), a7);
            }
            // reduce across the 8 edge-groups (lane bits 3..5)
            for (int m = 8; m <= 32; m <<= 1) {
                a0 += __shfl_xor(a0, m, 64);
                a1 += __shfl_xor(a1, m, 64);
                a2 += __shfl_xor(a2, m, 64);
                a3 += __shfl_xor(a3, m, 64);
                a4 += __shfl_xor(a4, m, 64);
                a5 += __shfl_xor(a5, m, 64);
                a6 += __shfl_xor(a6, m, 64);
                a7 += __shfl_xor(a7, m, 64);
            }
            if (lane < 8) {
                float4* ap = (float4*)&acc[r * D + lane * 8];
                float4 q0 = ap[0], q1 = ap[1];
                q0.x += a0; q0.y += a1; q0.z += a2; q0.w += a3;
                q1.x += a4; q1.y += a5; q1.z += a6; q1.w += a7;
                ap[0] = q0; ap[1] = q1;
            }
        }
    }
    __syncthreads();
    // write out 64 rows x 64 floats, coalesced float4
    float* __restrict__ outp = item_side ? h_item : h_user;
    const int limit = item_side ? N_ITEMS : N_USERS;
#pragma unroll
    for (int it = 0; it < 4; it++) {
        const int i4 = tid + it * 256;          // float4 index in [0,1024)
        const int r = (i4 * 4) >> 6;
        const int row = baseRow + r;
        if (row < limit) {
            *(float4*)&outp[(long long)row * D + ((i4 * 4) & 63)] = *(float4*)&acc[i4 * 4];
        }
    }
}

// ---------------- fallback: atomic scatter (round-1 proven) ----------------
__global__ void scatter_rel_kernel(const float* __restrict__ feat,
                                   const float* __restrict__ norm,
                                   const int* __restrict__ src,
                                   const int* __restrict__ dst,
                                   float* __restrict__ out, int n_edges) {
    const int lane = threadIdx.x & 63;
    const int wib = threadIdx.x >> 6;
    const int wpb = blockDim.x >> 6;
    long long e = (long long)blockIdx.x * wpb + wib;
    const long long stride = (long long)gridDim.x * wpb;
    for (; e < n_edges; e += stride) {
        atomicAdd(&out[(long long)dst[e] * D + lane],
                  norm[e] * feat[(long long)src[e] * D + lane]);
    }
}

extern "C" void kernel_launch(void* const* d_in, const int* in_sizes, int n_in,
                              void* d_out, int out_size, void* d_ws, size_t ws_size,
                              hipStream_t stream) {
    const float* user_feat = (const float*)d_in[0];
    const float* item_feat = (const float*)d_in[1];
    const float* norm_ui   = (const float*)d_in[2];
    const float* norm_iu   = (const float*)d_in[3];
    const int*   ui_src    = (const int*)d_in[4];  // user idx
    const int*   ui_dst    = (const int*)d_in[5];  // item idx
    const int*   iu_src    = (const int*)d_in[6];  // item idx
    const int*   iu_dst    = (const int*)d_in[7];  // user idx

    const int n_ui = in_sizes[4];
    const int n_iu = in_sizes[6];
    const int n_total = n_ui + n_iu;

    float* h_user = (float*)d_out;                              // [N_USERS, D]
    float* h_item = (float*)d_out + (long long)N_USERS * D;     // [N_ITEMS, D]

    const int block = 256;
    const int NB_ui = (n_ui + CHUNK - 1) / CHUNK;
    const int NB_iu = (n_iu + CHUNK - 1) / CHUNK;
    const int NB = NB_ui + NB_iu;
    const int scan_n = B_TOT * NB;
    const int ntiles = (scan_n + SCAN_TILE - 1) / SCAN_TILE;

    // ---- workspace layout ----
    char* ws = (char*)d_ws;
    size_t off = 0;
    int* counts = (int*)(ws + off);  off += align16((size_t)scan_n * 4);
    int* tsums  = (int*)(ws + off);  off += align16((size_t)2048 * 4);
    int2* part  = (int2*)(ws + off); off += align16((size_t)n_total * 8);
    unsigned int* user16 = (unsigned int*)(ws + off); off += align16((size_t)N_USERS * D * 2);
    unsigned int* item16 = (unsigned int*)(ws + off); off += align16((size_t)N_ITEMS * D * 2);
    const size_t needed = off;

    if (ws_size < needed || ntiles > 2048) {
        // fallback: atomic-scatter path
        hipMemsetAsync(d_out, 0, (size_t)out_size * sizeof(float), stream);
        const int wpb = block / 64;
        scatter_rel_kernel<<<(n_ui + wpb - 1) / wpb, block, 0, stream>>>(
            user_feat, norm_ui, ui_src, ui_dst, h_item, n_ui);
        scatter_rel_kernel<<<(n_iu + wpb - 1) / wpb, block, 0, stream>>>(
            item_feat, norm_iu, iu_src, iu_dst, h_user, n_iu);
        return;
    }

    // 0. fp32 -> bf16 feature tables
    const long long cv_threads = ((long long)(N_USERS + N_ITEMS) * D) / 4;
    convert_feats_kernel<<<(int)((cv_threads + block - 1) / block), block, 0, stream>>>(
        user_feat, item_feat, user16, item16);

    // 1. per-chunk bucket histograms (LDS atomics only)
    p1_count_kernel<<<NB, block, 0, stream>>>(ui_dst, iu_dst, counts,
                                              n_ui, n_iu, NB_ui, NB);

    // 2. exclusive scan of counts (bucket-major)
    scanA_kernel<<<ntiles, 256, 0, stream>>>(counts, tsums, scan_n);
    scanB_big_kernel<<<1, 1024, 0, stream>>>(tsums, ntiles);
    scanC_kernel<<<ntiles, 256, 0, stream>>>(counts, tsums, scan_n);

    // 3. scatter edges into bucket-grouped order
    p1_scatter_kernel<<<NB, block, 0, stream>>>(ui_src, iu_src, ui_dst, iu_dst,
                                                norm_ui, norm_iu, counts, part,
                                                n_ui, n_iu, NB_ui, NB);

    // 4. fused sort+gather, one block per bucket (writes every output row)
    p2_gather_kernel<<<B_TOT, block, 0, stream>>>(
        (const uint4*)user16, (const uint4*)item16, part, counts,
        h_user, h_item, NB, n_total);
}